// Round 8
// baseline (126.390 us; speedup 1.0000x reference)
//
#include <hip/hip_runtime.h>
#include <hip/hip_bf16.h>

#define NN   50000
#define NE   1600000
#define D    128
#define NBUK 391      // ceil(NN/128) buckets of 128 nodes
#define CAP  5120     // per-bucket edge capacity (mean 4092, +16 sigma)
#define EPB  4096     // edges per bfill block (512 thr x 8)
#define ASTR 136      // aggL row stride in ushorts (272 B: 16B-aligned, bank-friendly)
#define PREP_BLKS 3125   // 1.6M float4-groups / 512
#define WPREP_BLKS 32    // 16384 threads / 512

typedef __attribute__((ext_vector_type(8))) short short8;
typedef __attribute__((ext_vector_type(4))) float f32x4;

__device__ __forceinline__ unsigned short f2b(float x) {
  unsigned u = __float_as_uint(x);
  u += 0x7fffu + ((u >> 16) & 1u);
  return (unsigned short)(u >> 16);
}
__device__ __forceinline__ float b2f(unsigned v) {
  return __uint_as_float(v << 16);
}
__device__ __forceinline__ float b2fh(unsigned v) {
  return __uint_as_float(v & 0xffff0000u);
}

// Fused: [blocks 0..390] bucket-fill with inline int64-detect;
//        [391..3515] h->bf16; [3516..3547] weight fold W2@Wmsg -> bf16.
__global__ __launch_bounds__(512) void fused_k(const float* __restrict__ h,
                                               unsigned short* __restrict__ hb,
                                               int* __restrict__ gcur,
                                               const float* __restrict__ Wm,
                                               const float* __restrict__ Wu,
                                               unsigned short* __restrict__ W1b,
                                               unsigned short* __restrict__ Wcb,
                                               const int* __restrict__ ei,
                                               unsigned* __restrict__ ebuf) {
  __shared__ int cnt[NBUK];
  __shared__ int off[NBUK];
  __shared__ int nz;
  const int blk = blockIdx.x, tid = threadIdx.x;

  if (blk >= NBUK) {
    if (blk < NBUK + PREP_BLKS) {          // prep: h -> bf16
      int i = (blk - NBUK) * 512 + tid;    // one float4-group
      float4 x = ((const float4*)h)[i];
      ushort4 o;
      o.x = f2b(x.x); o.y = f2b(x.y); o.z = f2b(x.z); o.w = f2b(x.w);
      ((ushort4*)hb)[i] = o;
    } else {                               // wprep
      int t2 = (blk - NBUK - PREP_BLKS) * 512 + tid;
      if (t2 < 16384) {
        int o = t2 >> 7, j = t2 & 127;
        W1b[t2] = f2b(Wu[o * 256 + j]);
        float acc = 0.f;
#pragma unroll 4
        for (int k = 0; k < 128; ++k)
          acc += Wu[o * 256 + 128 + k] * Wm[k * 128 + j];
        Wcb[t2] = f2b(acc);
      }
    }
    return;
  }

  // ---- bfill: inline detect (odd int32 words all-zero => int64) ----
  if (tid == 0) nz = 0;
  if (tid < NBUK) cnt[tid] = 0;
  __syncthreads();
  if (tid < 256) {
    int idx = 1 + 2 * (tid * (NE / 256));
    if (ei[idx] != 0) atomicOr(&nz, 1);
  }
  __syncthreads();
  const int f = (nz == 0);

  const int e0 = blk * EPB + tid * 8;
  unsigned pk[8]; int bk[8]; int lr[8];
  if (e0 + 8 <= NE) {
    int sv[8], dv[8];
    if (f) {
      const int4* ps = (const int4*)(ei + 2 * (size_t)e0);
      const int4* pd = (const int4*)(ei + 2 * (size_t)NE + 2 * (size_t)e0);
      int4 a = ps[0], b = ps[1], c = ps[2], d = ps[3];
      sv[0]=a.x; sv[1]=a.z; sv[2]=b.x; sv[3]=b.z; sv[4]=c.x; sv[5]=c.z; sv[6]=d.x; sv[7]=d.z;
      a = pd[0]; b = pd[1]; c = pd[2]; d = pd[3];
      dv[0]=a.x; dv[1]=a.z; dv[2]=b.x; dv[3]=b.z; dv[4]=c.x; dv[5]=c.z; dv[6]=d.x; dv[7]=d.z;
    } else {
      const int4* ps = (const int4*)(ei + e0);
      const int4* pd = (const int4*)(ei + (size_t)NE + e0);
      int4 a = ps[0], b = ps[1];
      sv[0]=a.x; sv[1]=a.y; sv[2]=a.z; sv[3]=a.w; sv[4]=b.x; sv[5]=b.y; sv[6]=b.z; sv[7]=b.w;
      a = pd[0]; b = pd[1];
      dv[0]=a.x; dv[1]=a.y; dv[2]=a.z; dv[3]=a.w; dv[4]=b.x; dv[5]=b.y; dv[6]=b.z; dv[7]=b.w;
    }
#pragma unroll
    for (int j = 0; j < 8; ++j) {
      bk[j] = dv[j] >> 7;
      pk[j] = (unsigned)sv[j] | ((unsigned)(dv[j] & 127) << 16);
      lr[j] = atomicAdd(&cnt[bk[j]], 1);
    }
  } else {
    for (int j = 0; j < 8; ++j) {
      int e = e0 + j;
      bk[j] = -1;
      if (e < NE) {
        int src = f ? ei[2 * (size_t)e] : ei[e];
        int dst = f ? ei[2 * ((size_t)NE + e)] : ei[NE + e];
        bk[j] = dst >> 7;
        pk[j] = (unsigned)src | ((unsigned)(dst & 127) << 16);
        lr[j] = atomicAdd(&cnt[bk[j]], 1);
      }
    }
  }
  __syncthreads();
  if (tid < NBUK)
    off[tid] = cnt[tid] ? atomicAdd(&gcur[tid], cnt[tid]) : 0;
  __syncthreads();
#pragma unroll
  for (int j = 0; j < 8; ++j) {
    if (bk[j] >= 0) {
      int idx = off[bk[j]] + lr[j];
      if (idx < CAP) ebuf[(size_t)bk[j] * CAP + idx] = pk[j];
    }
  }
}

// One block per bucket (512 thr, 8 waves):
//  (1) counting-sort edges into LDS srt;
//  (2) each wave aggregates 16 node rows: 4 rows per dwordx4 instruction
//      (quarter-wave per row), 8-deep unroll -> 32 edges in flight, fp32
//      register accumulation, shfl_xor fold, bf16 row into LDS aggL;
//  (3) MFMA epilogue [hb | aggL] x [W1|Wc]^T + bias, ReLU -> out.
__global__ __launch_bounds__(512, 6) void sortagg_k(const unsigned* __restrict__ ebuf,
                                                    const int* __restrict__ gcur,
                                                    const unsigned short* __restrict__ hb,
                                                    const unsigned short* __restrict__ W1b,
                                                    const unsigned short* __restrict__ Wcb,
                                                    const float* __restrict__ bias,
                                                    float* __restrict__ out) {
  __shared__ unsigned short srt[CAP];
  __shared__ __align__(16) unsigned short aggL[128 * ASTR];
  __shared__ int cnt[128];
  __shared__ int ofs[129];
  __shared__ int cur[128];
  __shared__ int wsum[2];
  const int b = blockIdx.x, tid = threadIdx.x;
  const int lane = tid & 63, wv = tid >> 6;  // 8 waves
  if (tid < 128) cnt[tid] = 0;
  __syncthreads();
  const int count = min(gcur[b], CAP);
  const unsigned* eb = ebuf + (size_t)b * CAP;
  for (int e = tid; e < count; e += 512)
    atomicAdd(&cnt[eb[e] >> 16], 1);
  __syncthreads();
  int v = 0, s = 0;
  if (tid < 128) {  // waves 0,1: wave-uniform scan of 128 counters
    v = cnt[tid]; s = v;
#pragma unroll
    for (int d = 1; d < 64; d <<= 1) {
      int t = __shfl_up(s, d, 64);
      if (lane >= d) s += t;
    }
    if (lane == 63) wsum[wv] = s;
  }
  __syncthreads();
  if (tid < 128) {
    int excl = (wv ? wsum[0] : 0) + s - v;
    ofs[tid] = excl;
    cur[tid] = excl;
  }
  if (tid == 0) ofs[128] = count;
  __syncthreads();
  for (int e = tid; e < count; e += 512) {
    unsigned p = eb[e];
    int slot = atomicAdd(&cur[p >> 16], 1);
    srt[slot] = (unsigned short)(p & 0xffffu);
  }
  __syncthreads();

  // ---- aggregation: wave wv owns local nodes wv*16 .. wv*16+15 ----
  const int q = lane >> 4;        // quarter: which of 4 rows per instr
  const int r = lane & 15;        // 16B slice within row (channels 8r..8r+7)
  const unsigned short* hbl = hb + r * 8;
#pragma unroll 1
  for (int k = 0; k < 16; ++k) {
    const int n = wv * 16 + k;
    const int beg = ofs[n], end = ofs[n + 1];
    float a0=0.f,a1=0.f,a2=0.f,a3=0.f,a4=0.f,a5=0.f,a6=0.f,a7=0.f;
    int e = beg;
    for (; e + 32 <= end; e += 32) {   // 8 x dwordx4 = 32 edges in flight
      uint4 vv[8];
#pragma unroll
      for (int j = 0; j < 8; ++j)
        vv[j] = *(const uint4*)(hbl + (size_t)srt[e + 4 * j + q] * D);
#pragma unroll
      for (int j = 0; j < 8; ++j) {
        a0 += b2f(vv[j].x & 0xffffu); a1 += b2fh(vv[j].x);
        a2 += b2f(vv[j].y & 0xffffu); a3 += b2fh(vv[j].y);
        a4 += b2f(vv[j].z & 0xffffu); a5 += b2fh(vv[j].z);
        a6 += b2f(vv[j].w & 0xffffu); a7 += b2fh(vv[j].w);
      }
    }
    for (; e < end; e += 4) {          // masked 4-edge tail
      int edge = e + q;
      int ce = min(edge, end - 1);
      uint4 vv = *(const uint4*)(hbl + (size_t)srt[ce] * D);
      if (edge >= end) { vv.x = 0u; vv.y = 0u; vv.z = 0u; vv.w = 0u; }
      a0 += b2f(vv.x & 0xffffu); a1 += b2fh(vv.x);
      a2 += b2f(vv.y & 0xffffu); a3 += b2fh(vv.y);
      a4 += b2f(vv.z & 0xffffu); a5 += b2fh(vv.z);
      a6 += b2f(vv.w & 0xffffu); a7 += b2fh(vv.w);
    }
    // fold quarters: every lane ends with full sums for channels 8r..8r+7
    a0 += __shfl_xor(a0, 16, 64); a0 += __shfl_xor(a0, 32, 64);
    a1 += __shfl_xor(a1, 16, 64); a1 += __shfl_xor(a1, 32, 64);
    a2 += __shfl_xor(a2, 16, 64); a2 += __shfl_xor(a2, 32, 64);
    a3 += __shfl_xor(a3, 16, 64); a3 += __shfl_xor(a3, 32, 64);
    a4 += __shfl_xor(a4, 16, 64); a4 += __shfl_xor(a4, 32, 64);
    a5 += __shfl_xor(a5, 16, 64); a5 += __shfl_xor(a5, 32, 64);
    a6 += __shfl_xor(a6, 16, 64); a6 += __shfl_xor(a6, 32, 64);
    a7 += __shfl_xor(a7, 16, 64); a7 += __shfl_xor(a7, 32, 64);
    if (lane < 16) {
      uint4 o;
      o.x = (unsigned)f2b(a0) | ((unsigned)f2b(a1) << 16);
      o.y = (unsigned)f2b(a2) | ((unsigned)f2b(a3) << 16);
      o.z = (unsigned)f2b(a4) | ((unsigned)f2b(a5) << 16);
      o.w = (unsigned)f2b(a6) | ((unsigned)f2b(a7) << 16);
      *(uint4*)(aggL + n * ASTR + r * 8) = o;
    }
  }
  __syncthreads();

  // ---- MFMA epilogue: wave wv = row-tile wv (16 rows), all 8 col-tiles ----
  const int rr = lane & 15, g = lane >> 4;
  const int rowL = wv * 16 + rr;
  const int nodeA = min(b * 128 + rowL, NN - 1);

  f32x4 acc[8];
#pragma unroll
  for (int t = 0; t < 8; ++t) acc[t] = (f32x4){0.f, 0.f, 0.f, 0.f};

#pragma unroll
  for (int c = 0; c < 8; ++c) {
    const int k0 = (c & 3) * 32 + g * 8;
    short8 a;
    if (c < 4) {
      a = *(const short8*)(hb + (size_t)nodeA * D + k0);
    } else {
      a = *(const short8*)(aggL + rowL * ASTR + k0);
    }
    const unsigned short* W = (c < 4) ? W1b : Wcb;
#pragma unroll
    for (int t = 0; t < 8; ++t) {
      short8 bfr = *(const short8*)(W + (size_t)(t * 16 + rr) * D + k0);
      acc[t] = __builtin_amdgcn_mfma_f32_16x16x32_bf16(a, bfr, acc[t], 0, 0, 0);
    }
  }

#pragma unroll
  for (int t = 0; t < 8; ++t) {
    const int col = t * 16 + rr;
    const float bv = bias[col];
#pragma unroll
    for (int j = 0; j < 4; ++j) {
      const int orow = b * 128 + wv * 16 + g * 4 + j;
      if (orow < NN) {
        float vv = acc[t][j] + bv;
        out[(size_t)orow * D + col] = vv > 0.f ? vv : 0.f;
      }
    }
  }
}

extern "C" void kernel_launch(void* const* d_in, const int* in_sizes, int n_in,
                              void* d_out, int out_size, void* d_ws, size_t ws_size,
                              hipStream_t stream) {
  const float* h  = (const float*)d_in[0];
  const int*   ei = (const int*)d_in[1];
  const float* Wm = (const float*)d_in[2];
  const float* Wu = (const float*)d_in[3];
  const float* bu = (const float*)d_in[4];
  float* out = (float*)d_out;

  char* ws = (char*)d_ws;
  unsigned short* hb   = (unsigned short*)(ws);              // 12,800,000 B
  unsigned*       ebuf = (unsigned*)(ws + 12800000);         //  8,007,680 B (391*5120*4)
  int*            gcur = (int*)(ws + 20807680);              //      2,048 B
  unsigned short* W1b  = (unsigned short*)(ws + 20809728);   //     32,768 B
  unsigned short* Wcb  = (unsigned short*)(ws + 20842496);   //     32,768 B

  hipMemsetAsync(gcur, 0, NBUK * sizeof(int), stream);
  fused_k<<<NBUK + PREP_BLKS + WPREP_BLKS, 512, 0, stream>>>(
      h, hb, gcur, Wm, Wu, W1b, Wcb, ei, ebuf);                     // 3548 blocks
  sortagg_k<<<NBUK, 512, 0, stream>>>(ebuf, gcur, hb, W1b, Wcb, bu, out);  // 391
}

// Round 9
// 121.319 us; speedup vs baseline: 1.0418x; 1.0418x over previous
//
#include <hip/hip_runtime.h>
#include <hip/hip_bf16.h>

#define NN   50000
#define NE   1600000
#define D    128
#define NBK  782      // ceil(NN/64) buckets of 64 nodes
#define CAP2 2816     // per-bucket capacity (mean 2048, +17 sigma)
#define EPB  4096     // edges per fill block (512 thr x 8)
#define FILLB 391     // NE / EPB (rounded up)
#define ASTR 136      // aggL row stride in ushorts (272 B)
#define PREP_BLKS 3125   // 1.6M float4-groups / 512
#define WPREP_BLKS 32    // 16384 threads / 512

typedef __attribute__((ext_vector_type(8))) short short8;
typedef __attribute__((ext_vector_type(4))) float f32x4;

__device__ __forceinline__ unsigned short f2b(float x) {
  unsigned u = __float_as_uint(x);
  u += 0x7fffu + ((u >> 16) & 1u);
  return (unsigned short)(u >> 16);
}
__device__ __forceinline__ float b2f(unsigned v) {
  return __uint_as_float(v << 16);
}
__device__ __forceinline__ float b2fh(unsigned v) {
  return __uint_as_float(v & 0xffff0000u);
}

// Fused: [blocks 0..FILLB-1] bucket-fill (inline int64-detect);
//        [FILLB..] h->bf16 prep; then weight fold W2@Wmsg -> bf16.
__global__ __launch_bounds__(512) void fused_k(const float* __restrict__ h,
                                               unsigned short* __restrict__ hb,
                                               int* __restrict__ gcur,
                                               const float* __restrict__ Wm,
                                               const float* __restrict__ Wu,
                                               unsigned short* __restrict__ W1b,
                                               unsigned short* __restrict__ Wcb,
                                               const int* __restrict__ ei,
                                               unsigned* __restrict__ ebuf) {
  __shared__ int cnt[NBK];
  __shared__ int off[NBK];
  __shared__ int nz;
  const int blk = blockIdx.x, tid = threadIdx.x;

  if (blk >= FILLB) {
    if (blk < FILLB + PREP_BLKS) {         // prep: h -> bf16
      int i = (blk - FILLB) * 512 + tid;   // one float4-group
      float4 x = ((const float4*)h)[i];
      ushort4 o;
      o.x = f2b(x.x); o.y = f2b(x.y); o.z = f2b(x.z); o.w = f2b(x.w);
      ((ushort4*)hb)[i] = o;
    } else {                               // wprep
      int t2 = (blk - FILLB - PREP_BLKS) * 512 + tid;
      if (t2 < 16384) {
        int o = t2 >> 7, j = t2 & 127;
        W1b[t2] = f2b(Wu[o * 256 + j]);
        float acc = 0.f;
#pragma unroll 4
        for (int k = 0; k < 128; ++k)
          acc += Wu[o * 256 + 128 + k] * Wm[k * 128 + j];
        Wcb[t2] = f2b(acc);
      }
    }
    return;
  }

  // ---- bfill: inline detect (odd int32 words all-zero => int64) ----
  if (tid == 0) nz = 0;
  for (int t = tid; t < NBK; t += 512) cnt[t] = 0;
  __syncthreads();
  if (tid < 256) {
    int idx = 1 + 2 * (tid * (NE / 256));
    if (ei[idx] != 0) atomicOr(&nz, 1);
  }
  __syncthreads();
  const int f = (nz == 0);

  const int e0 = blk * EPB + tid * 8;
  unsigned pk[8]; int bk[8]; int lr[8];
  if (e0 + 8 <= NE) {
    int sv[8], dv[8];
    if (f) {
      const int4* ps = (const int4*)(ei + 2 * (size_t)e0);
      const int4* pd = (const int4*)(ei + 2 * (size_t)NE + 2 * (size_t)e0);
      int4 a = ps[0], b = ps[1], c = ps[2], d = ps[3];
      sv[0]=a.x; sv[1]=a.z; sv[2]=b.x; sv[3]=b.z; sv[4]=c.x; sv[5]=c.z; sv[6]=d.x; sv[7]=d.z;
      a = pd[0]; b = pd[1]; c = pd[2]; d = pd[3];
      dv[0]=a.x; dv[1]=a.z; dv[2]=b.x; dv[3]=b.z; dv[4]=c.x; dv[5]=c.z; dv[6]=d.x; dv[7]=d.z;
    } else {
      const int4* ps = (const int4*)(ei + e0);
      const int4* pd = (const int4*)(ei + (size_t)NE + e0);
      int4 a = ps[0], b = ps[1];
      sv[0]=a.x; sv[1]=a.y; sv[2]=a.z; sv[3]=a.w; sv[4]=b.x; sv[5]=b.y; sv[6]=b.z; sv[7]=b.w;
      a = pd[0]; b = pd[1];
      dv[0]=a.x; dv[1]=a.y; dv[2]=a.z; dv[3]=a.w; dv[4]=b.x; dv[5]=b.y; dv[6]=b.z; dv[7]=b.w;
    }
#pragma unroll
    for (int j = 0; j < 8; ++j) {
      bk[j] = dv[j] >> 6;
      pk[j] = (unsigned)sv[j] | ((unsigned)(dv[j] & 63) << 16);
      lr[j] = atomicAdd(&cnt[bk[j]], 1);
    }
  } else {
    for (int j = 0; j < 8; ++j) {
      int e = e0 + j;
      bk[j] = -1;
      if (e < NE) {
        int src = f ? ei[2 * (size_t)e] : ei[e];
        int dst = f ? ei[2 * ((size_t)NE + e)] : ei[NE + e];
        bk[j] = dst >> 6;
        pk[j] = (unsigned)src | ((unsigned)(dst & 63) << 16);
        lr[j] = atomicAdd(&cnt[bk[j]], 1);
      }
    }
  }
  __syncthreads();
  for (int t = tid; t < NBK; t += 512)
    off[t] = cnt[t] ? atomicAdd(&gcur[t], cnt[t]) : 0;
  __syncthreads();
#pragma unroll
  for (int j = 0; j < 8; ++j) {
    if (bk[j] >= 0) {
      int idx = off[bk[j]] + lr[j];
      if (idx < CAP2) ebuf[(size_t)bk[j] * CAP2 + idx] = pk[j];
    }
  }
}

// One block per 64-node bucket (512 thr, 8 waves):
//  (1) counting-sort edges into LDS srt (64-counter hist + 1-wave scan);
//  (2) wave wv aggregates nodes wv*8..wv*8+7: 4 rows per dwordx4 gather
//      (quarter-wave per row), 16-edge unroll, fp32 regs, shfl_xor fold,
//      bf16 row to LDS aggL;
//  (3) MFMA epilogue [hb | aggL] x [W1|Wc]^T + bias, ReLU -> out.
__global__ __launch_bounds__(512, 4) void sortagg_k(const unsigned* __restrict__ ebuf,
                                                    const int* __restrict__ gcur,
                                                    const unsigned short* __restrict__ hb,
                                                    const unsigned short* __restrict__ W1b,
                                                    const unsigned short* __restrict__ Wcb,
                                                    const float* __restrict__ bias,
                                                    float* __restrict__ out) {
  __shared__ unsigned short srt[CAP2];                       //  5,632 B
  __shared__ __align__(16) unsigned short aggL[64 * ASTR];   // 17,408 B
  __shared__ int cnt[64];
  __shared__ int ofs[65];
  __shared__ int cur[64];
  const int b = blockIdx.x, tid = threadIdx.x;
  const int lane = tid & 63, wv = tid >> 6;  // 8 waves
  if (tid < 64) cnt[tid] = 0;
  __syncthreads();
  const int count = min(gcur[b], CAP2);
  const unsigned* eb = ebuf + (size_t)b * CAP2;
  for (int e = tid; e < count; e += 512)
    atomicAdd(&cnt[eb[e] >> 16], 1);
  __syncthreads();
  if (wv == 0) {  // single-wave scan of 64 counters
    int v = cnt[lane], s = v;
#pragma unroll
    for (int d = 1; d < 64; d <<= 1) {
      int t = __shfl_up(s, d, 64);
      if (lane >= d) s += t;
    }
    ofs[lane] = s - v;
    cur[lane] = s - v;
    if (lane == 63) ofs[64] = count;
  }
  __syncthreads();
  for (int e = tid; e < count; e += 512) {
    unsigned p = eb[e];
    int slot = atomicAdd(&cur[p >> 16], 1);
    srt[slot] = (unsigned short)(p & 0xffffu);
  }
  __syncthreads();

  // ---- aggregation: wave wv owns local nodes wv*8 .. wv*8+7 ----
  const int q = lane >> 4;        // quarter: which of 4 rows per instr
  const int r = lane & 15;        // 16B slice within row (channels 8r..8r+7)
  const unsigned short* hbl = hb + r * 8;
#pragma unroll 1
  for (int k = 0; k < 8; ++k) {
    const int n = wv * 8 + k;
    const int beg = ofs[n], end = ofs[n + 1];
    float a0=0.f,a1=0.f,a2=0.f,a3=0.f,a4=0.f,a5=0.f,a6=0.f,a7=0.f;
    int e = beg;
    for (; e + 16 <= end; e += 16) {   // 4 x dwordx4 = 16 edges in flight
      uint4 vv[4];
#pragma unroll
      for (int j = 0; j < 4; ++j)
        vv[j] = *(const uint4*)(hbl + (size_t)srt[e + 4 * j + q] * D);
#pragma unroll
      for (int j = 0; j < 4; ++j) {
        a0 += b2f(vv[j].x & 0xffffu); a1 += b2fh(vv[j].x);
        a2 += b2f(vv[j].y & 0xffffu); a3 += b2fh(vv[j].y);
        a4 += b2f(vv[j].z & 0xffffu); a5 += b2fh(vv[j].z);
        a6 += b2f(vv[j].w & 0xffffu); a7 += b2fh(vv[j].w);
      }
    }
    for (; e < end; e += 4) {          // masked 4-edge tail
      int edge = e + q;
      int ce = min(edge, end - 1);
      uint4 vv = *(const uint4*)(hbl + (size_t)srt[ce] * D);
      if (edge >= end) { vv.x = 0u; vv.y = 0u; vv.z = 0u; vv.w = 0u; }
      a0 += b2f(vv.x & 0xffffu); a1 += b2fh(vv.x);
      a2 += b2f(vv.y & 0xffffu); a3 += b2fh(vv.y);
      a4 += b2f(vv.z & 0xffffu); a5 += b2fh(vv.z);
      a6 += b2f(vv.w & 0xffffu); a7 += b2fh(vv.w);
    }
    // fold quarters: all lanes end with full sums for channels 8r..8r+7
    a0 += __shfl_xor(a0, 16, 64); a0 += __shfl_xor(a0, 32, 64);
    a1 += __shfl_xor(a1, 16, 64); a1 += __shfl_xor(a1, 32, 64);
    a2 += __shfl_xor(a2, 16, 64); a2 += __shfl_xor(a2, 32, 64);
    a3 += __shfl_xor(a3, 16, 64); a3 += __shfl_xor(a3, 32, 64);
    a4 += __shfl_xor(a4, 16, 64); a4 += __shfl_xor(a4, 32, 64);
    a5 += __shfl_xor(a5, 16, 64); a5 += __shfl_xor(a5, 32, 64);
    a6 += __shfl_xor(a6, 16, 64); a6 += __shfl_xor(a6, 32, 64);
    a7 += __shfl_xor(a7, 16, 64); a7 += __shfl_xor(a7, 32, 64);
    if (lane < 16) {
      uint4 o;
      o.x = (unsigned)f2b(a0) | ((unsigned)f2b(a1) << 16);
      o.y = (unsigned)f2b(a2) | ((unsigned)f2b(a3) << 16);
      o.z = (unsigned)f2b(a4) | ((unsigned)f2b(a5) << 16);
      o.w = (unsigned)f2b(a6) | ((unsigned)f2b(a7) << 16);
      *(uint4*)(aggL + n * ASTR + r * 8) = o;
    }
  }
  __syncthreads();

  // ---- MFMA epilogue: 4 row-tiles x 8 col-tiles; wave pair splits cols ----
  const int rr = lane & 15, g = lane >> 4;
  const int rtile = wv >> 1;         // 0..3
  const int t0 = (wv & 1) * 4;       // col-tile offset 0 or 4
  const int rowL = rtile * 16 + rr;
  const int nodeA = min(b * 64 + rowL, NN - 1);

  f32x4 acc[4];
#pragma unroll
  for (int t = 0; t < 4; ++t) acc[t] = (f32x4){0.f, 0.f, 0.f, 0.f};

#pragma unroll
  for (int c = 0; c < 8; ++c) {
    const int k0 = (c & 3) * 32 + g * 8;
    short8 a;
    if (c < 4) {
      a = *(const short8*)(hb + (size_t)nodeA * D + k0);
    } else {
      a = *(const short8*)(aggL + rowL * ASTR + k0);
    }
    const unsigned short* W = (c < 4) ? W1b : Wcb;
#pragma unroll
    for (int tt = 0; tt < 4; ++tt) {
      short8 bfr = *(const short8*)(W + (size_t)((t0 + tt) * 16 + rr) * D + k0);
      acc[tt] = __builtin_amdgcn_mfma_f32_16x16x32_bf16(a, bfr, acc[tt], 0, 0, 0);
    }
  }

#pragma unroll
  for (int tt = 0; tt < 4; ++tt) {
    const int col = (t0 + tt) * 16 + rr;
    const float bv = bias[col];
#pragma unroll
    for (int j = 0; j < 4; ++j) {
      const int orow = b * 64 + rtile * 16 + g * 4 + j;
      if (orow < NN) {
        float vv = acc[tt][j] + bv;
        out[(size_t)orow * D + col] = vv > 0.f ? vv : 0.f;
      }
    }
  }
}

extern "C" void kernel_launch(void* const* d_in, const int* in_sizes, int n_in,
                              void* d_out, int out_size, void* d_ws, size_t ws_size,
                              hipStream_t stream) {
  const float* h  = (const float*)d_in[0];
  const int*   ei = (const int*)d_in[1];
  const float* Wm = (const float*)d_in[2];
  const float* Wu = (const float*)d_in[3];
  const float* bu = (const float*)d_in[4];
  float* out = (float*)d_out;

  char* ws = (char*)d_ws;
  unsigned short* hb   = (unsigned short*)(ws);              // 12,800,000 B
  unsigned*       ebuf = (unsigned*)(ws + 12800000);         //  8,808,448 B (782*2816*4)
  int*            gcur = (int*)(ws + 21608448);              //      3,128 B
  unsigned short* W1b  = (unsigned short*)(ws + 21611576 + 8); //   32,768 B (16B-aligned region below)
  unsigned short* Wcb  = (unsigned short*)(ws + 21644352);   //     32,768 B

  hipMemsetAsync(gcur, 0, NBK * sizeof(int), stream);
  fused_k<<<FILLB + PREP_BLKS + WPREP_BLKS, 512, 0, stream>>>(
      h, hb, gcur, Wm, Wu, W1b, Wcb, ei, ebuf);                       // 3548 blocks
  sortagg_k<<<NBK, 512, 0, stream>>>(ebuf, gcur, hb, W1b, Wcb, bu, out);  // 782
}